// Round 9
// baseline (183.106 us; speedup 1.0000x reference)
//
#include <hip/hip_runtime.h>

#define Bn 256
#define Sn 1024
#define Tn 64
#define NCH 16
#define NGRP 32
#define BURN 64
#define SLAB 4
#define CROW 72             // conv bf16 row stride in shorts
#define MROW 129
#define LN2 0.69314718055994531f
#define L7LN2 4.8520302639196169f   // 7*ln2 (lambda = 2^-7 folded into exp)

typedef __attribute__((ext_vector_type(8))) short short8;
typedef __attribute__((ext_vector_type(4))) float f32x4;

__device__ __forceinline__ unsigned short f2bf_rne(float f) {
  unsigned u = __float_as_uint(f);
  u = (u + 0x7fffu + ((u >> 16) & 1u)) >> 16;
  return (unsigned short)u;
}
__device__ __forceinline__ unsigned pk2(float hi, float lo) {
  return __builtin_amdgcn_perm(__float_as_uint(hi), __float_as_uint(lo), 0x07060302);
}
__device__ __forceinline__ unsigned pke(float a, float b) {  // exp+pack 2 bf16
  return (unsigned)f2bf_rne(__expf(a - L7LN2)) |
         ((unsigned)f2bf_rne(__expf(b - L7LN2)) << 16);
}
// concat two uint2 (4 bf16 each) into a short8 MFMA operand — register-only.
__device__ __forceinline__ short8 cat4(uint2 a, uint2 b) {
  union { unsigned u[4]; short8 s; } x;
  x.u[0] = a.x; x.u[1] = a.y; x.u[2] = b.x; x.u[3] = b.y;
  return x.s;
}
// async global->LDS (kept ONLY for the small mask staging)
__device__ __forceinline__ void gl_lds4(const void* src, void* dst) {
  __builtin_amdgcn_global_load_lds(
      (const __attribute__((address_space(1))) void*)src,
      (__attribute__((address_space(3))) void*)dst, 4, 0, 0);
}

// R9: TWO BLOCKS PER CU. R1-R8 invariant: per-CU em delivery pinned at
// ~2.5 B/cy in EVERY 1-block/CU schedule (deep queues, multi-issuer,
// counted vmcnt all flat) — the one never-moved variable is blocks/CU.
// Split each 16-row group into two 8-row blocks: grid 512 (32 grp x 16
// chunks), 4 waves each -> 8 waves/CU in two INDEPENDENT barrier groups
// (decoupled pipelines keep the memory pipe busy while the sibling block
// barriers). Same total HBM bytes; scan chain unchanged; MFMA lanes m>=8
// compute discarded duplicate columns (MFMA is 1.8% util — free).
// Conv: 8 rows x 8 state-octets, all 64 lanes, bit-identical convS
// (state 8k+j -> pos 32(k>>2)+16(j>>2)+4(k&3)+(j&3); same pke order).
//   wave0: renorm + 4-step MFMA scan    wave1: em loads+conv u={0,1}
//   wave2: em loads+conv u={2,3}        wave3: mask + gold (prologue only)
// Register-resident alpha via permuted A rows (rho) — D-layout == B-layout.
// Fused finale: last of 512 blocks reduces everything to out[0].
__global__ __launch_bounds__(256, 2) void crf_scan(
    const float* __restrict__ em, const int* __restrict__ tags,
    const int* __restrict__ mask, const float* __restrict__ trans,
    const float* __restrict__ startt, const float* __restrict__ endt,
    float* __restrict__ wsL, float* __restrict__ wsGold,
    int* __restrict__ wsM, float* __restrict__ wsSE, float* __restrict__ wsA,
    int* __restrict__ cnt, float* __restrict__ out) {
  const int g = blockIdx.x & 31;          // row-group: rows 8g..8g+7
  const int c = blockIdx.x >> 5;          // chunk
  const int Wc = (c == 0) ? 0 : BURN;
  const int Lc = (c == NCH - 1) ? 63 : 64;
  const int TOT = Wc + Lc;
  const int NSLAB = (TOT + SLAB - 1) / SLAB;   // 16 (c==0) or 32
  const int t0 = 64 * c + 1;
  const int tstart = t0 - Wc;
  const int tid = threadIdx.x;
  const int wid = tid >> 6;
  const int lane = tid & 63;
  const int m = lane & 15;
  const int q = lane >> 4;
  const int r8 = m & 7;                   // this lane's batch row (mod 8)
  const int mrow = 8 * (m >> 2) + (m & 3);  // permuted A-row base (states)

  __shared__ __align__(16) short convS[2][SLAB * 8 * CROW]; // 9.2 KB exp'd bf16
  __shared__ int maskL[8 * MROW];                           // 4.1 KB
  __shared__ int lastF;
  __shared__ float eend[64];
  __shared__ float rsum[4];

  short8 a00, a01, a10, a11, a20, a21, a30, a31;
  uint2 st0, st1, st2, st3;
  float Slog = 0.f;
  int K = 0, NL = 0;
  const f32x4 zero4 = {0.f, 0.f, 0.f, 0.f};

  // ================= conv-wave register staging =================
  // Lane (mm8_,seg8_): row 8g+mm8_, true states 8*seg8_..+7, timesteps
  // (ua, ua+1) per slab. FOUR named 4xfloat4 buffers (rule #20).
  const int mm8_ = lane & 7, seg8_ = lane >> 3;
  const int pos0_ = 32 * (seg8_ >> 2) + 4 * (seg8_ & 3);  // permuted dst
  const size_t rowoff = (size_t)(8 * g + mm8_) * Sn;
  const int ua = (wid == 1) ? 0 : 2;
  float4 A0, A1, A2, A3;   // slab s: s&3 == 0
  float4 B0, B1, B2, B3;   // s&3 == 1
  float4 C0, C1, C2, C3;   // s&3 == 2
  float4 D0, D1, D2, D3;   // s&3 == 3

#define LOADS(P, s) do { if ((s) < NSLAB) { \
    int ta_ = tstart + 4 * (s) + ua;  int tb_ = ta_ + 1; \
    ta_ = min(ta_, Sn - 1);  tb_ = min(tb_, Sn - 1);   /* c==15 tail clamp */ \
    const float* pa_ = em + (rowoff + ta_) * 64 + 8 * seg8_; \
    const float* pb_ = em + (rowoff + tb_) * 64 + 8 * seg8_; \
    P##0 = *(const float4*)(pa_);      P##1 = *(const float4*)(pa_ + 4); \
    P##2 = *(const float4*)(pb_);      P##3 = *(const float4*)(pb_ + 4); } } while (0)

  // states 8k+{0..3} -> pos0_, 8k+{4..7} -> pos0_+16; same pke order as R7/R8
#define CONVW(P, s) do { if ((s) < NSLAB) { \
    short* cb_ = convS[(s) & 1]; \
    uint2 w0_, w1_; \
    w0_.x = pke((P##0).x, (P##0).y); w0_.y = pke((P##0).z, (P##0).w); \
    w1_.x = pke((P##1).x, (P##1).y); w1_.y = pke((P##1).z, (P##1).w); \
    short* cw_ = cb_ + (ua * 8 + mm8_) * CROW + pos0_; \
    *(uint2*)(cw_) = w0_;  *(uint2*)(cw_ + 16) = w1_; \
    w0_.x = pke((P##2).x, (P##2).y); w0_.y = pke((P##2).z, (P##2).w); \
    w1_.x = pke((P##3).x, (P##3).y); w1_.y = pke((P##3).z, (P##3).w); \
    cw_ = cb_ + ((ua + 1) * 8 + mm8_) * CROW + pos0_; \
    *(uint2*)(cw_) = w0_;  *(uint2*)(cw_ + 16) = w1_; } } while (0)

  // ================= phase A (prologue) =================
  if (wid == 0) {
    // A_phys[j][k] = exp(trans[k][rho(j)]); rho uses full m (state axis!)
#define LOADA(tm, kc, dst) { \
    _Pragma("unroll") for (int jj = 0; jj < 8; ++jj) { \
      int kk = kc * 32 + q * 8 + jj; \
      dst[jj] = (short)f2bf_rne(__expf(trans[kk * Tn + (32 * ((tm) >> 1) + 4 * ((tm) & 1) + mrow)])); \
    } }
    LOADA(0, 0, a00) LOADA(0, 1, a01) LOADA(1, 0, a10) LOADA(1, 1, a11)
    LOADA(2, 0, a20) LOADA(2, 1, a21) LOADA(3, 0, a30) LOADA(3, 1, a31)
#undef LOADA
    if (c == 0) {  // exact alpha_0; lanes m>=8 duplicate row r8 (discarded)
#define INIT0(off, ss) { \
      float4 sv = *(const float4*)(startt + (off)); \
      float4 ev = *(const float4*)(em + (size_t)(8 * g + r8) * Sn * Tn + (off)); \
      ss.x = (unsigned)f2bf_rne(__expf(sv.x + ev.x)) | \
             ((unsigned)f2bf_rne(__expf(sv.y + ev.y)) << 16); \
      ss.y = (unsigned)f2bf_rne(__expf(sv.z + ev.z)) | \
             ((unsigned)f2bf_rne(__expf(sv.w + ev.w)) << 16); }
      INIT0(8 * q, st0) INIT0(8 * q + 4, st1)
      INIT0(32 + 8 * q, st2) INIT0(36 + 8 * q, st3)
#undef INIT0
    } else {
      st0.x = 0x3F803F80u; st0.y = 0x3F803F80u; st1 = st0; st2 = st0; st3 = st0;
    }
  } else if (wid == 3) {
    // ---- mask staging (async gl_lds, 8 rows) ----
    for (int mm = 0; mm < 8; ++mm) {
      gl_lds4(mask + (size_t)(8 * g + mm) * Sn + tstart + lane,
              (void*)(maskL + mm * MROW));
      bool special = (c == NCH - 1) && (g == NGRP - 1) && (mm == 7);  // OOB t=1024
      if (!special)
        gl_lds4(mask + (size_t)(8 * g + mm) * Sn + tstart + 64 + lane,
                (void*)(maskL + mm * MROW + 64));
    }
    // ---- gold partials (rows 8g+r8; lanes m>=8 duplicate, writes gated) ----
    {
      const int bm = 8 * g + r8;
      const int* tg = tags + (size_t)bm * Sn;
      const int* mkb = mask + (size_t)bm * Sn;
      const float* emb = em + (size_t)bm * Sn * Tn;
      float acc = 0.f;
      int cntg = 0;
      #pragma unroll 4
      for (int i = 0; i < 16; ++i) {
        int t = t0 + q + 4 * i;
        bool ok = t < t0 + Lc;
        int ts = ok ? t : t0;
        int mv = mkb[ts];
        int tp = tg[ts - 1], tc = tg[ts];
        float w = trans[tp * Tn + tc] + emb[(size_t)ts * Tn + tc];
        acc += (ok && mv) ? w : 0.f;
        cntg += ok ? mv : 0;
      }
      acc += __shfl_xor(acc, 16); acc += __shfl_xor(acc, 32);
      cntg += __shfl_xor(cntg, 16); cntg += __shfl_xor(cntg, 32);
      if (q == 0 && m < 8) { wsGold[c * 256 + bm] = acc; wsM[c * 256 + bm] = cntg; }
    }
    // repair the skipped mask row with guarded plain stores
    if (c == NCH - 1 && g == NGRP - 1) {
      int t = tstart + 64 + lane;
      if (t < Sn) maskL[7 * MROW + 64 + lane] = mask[(size_t)255 * Sn + t];
    }
    asm volatile("s_waitcnt vmcnt(0) lgkmcnt(0)" ::: "memory");
  } else {
    // conv waves: issue slabs 0-3 to regs (16 loads in flight); convert slab0
    LOADS(A, 0);
    LOADS(B, 1);
    LOADS(C, 2);
    LOADS(D, 3);
    CONVW(A, 0);          // dataflow-counted wait: only A's 4 loads
    asm volatile("s_waitcnt lgkmcnt(0)" ::: "memory");  // publish ds_writes
  }
  __builtin_amdgcn_s_barrier();   // convS[0] + maskL ready; slabs 1-3 flying
  asm volatile("" ::: "memory");

  // ================= rounds =================
#define UNP(ss, x0, x1, x2, x3) \
  x0 = __uint_as_float(ss.x << 16); x1 = __uint_as_float(ss.x & 0xffff0000u); \
  x2 = __uint_as_float(ss.y << 16); x3 = __uint_as_float(ss.y & 0xffff0000u);

  auto renorm = [&](int ttz) {  // every 8 steps, exact pow2 scaling
    float x00, x01, x02, x03, x10, x11, x12, x13;
    float x20, x21, x22, x23, x30, x31, x32, x33;
    UNP(st0, x00, x01, x02, x03) UNP(st1, x10, x11, x12, x13)
    UNP(st2, x20, x21, x22, x23) UNP(st3, x30, x31, x32, x33)
    float sm = (((x00 + x01) + (x02 + x03)) + ((x10 + x11) + (x12 + x13)))
             + (((x20 + x21) + (x22 + x23)) + ((x30 + x31) + (x32 + x33)));
    sm += __shfl_xor(sm, 16); sm += __shfl_xor(sm, 32);   // per-column (q dims)
    if (c != 0 && ttz == BURN) { Slog = __logf(sm); K = 0; NL = 0; }
    int k = 127 - (int)((__float_as_uint(sm) >> 23) & 255u);
    float fk = __uint_as_float((unsigned)(127 + k) << 23);
    x00 *= fk; x01 *= fk; x02 *= fk; x03 *= fk;
    x10 *= fk; x11 *= fk; x12 *= fk; x13 *= fk;
    x20 *= fk; x21 *= fk; x22 *= fk; x23 *= fk;
    x30 *= fk; x31 *= fk; x32 *= fk; x33 *= fk;
    st0.x = pk2(x01, x00); st0.y = pk2(x03, x02);
    st1.x = pk2(x11, x10); st1.y = pk2(x13, x12);
    st2.x = pk2(x21, x20); st2.y = pk2(x23, x22);
    st3.x = pk2(x31, x30); st3.y = pk2(x33, x32);
    K += k;
  };

  auto scan_step = [&](const short* ep, int tt) {
    uint2 eu0 = *(const uint2*)(ep + 0 + 4 * q);
    uint2 eu1 = *(const uint2*)(ep + 16 + 4 * q);
    uint2 eu2 = *(const uint2*)(ep + 32 + 4 * q);
    uint2 eu3 = *(const uint2*)(ep + 48 + 4 * q);
    int mv = maskL[r8 * MROW + tt];
    // D-layout == B-layout under the row permutation: pure reg concat.
    short8 b0 = cat4(st0, st1);
    short8 b1 = cat4(st2, st3);
    f32x4 d0 = __builtin_amdgcn_mfma_f32_16x16x32_bf16(a00, b0, zero4, 0, 0, 0);
    f32x4 d1 = __builtin_amdgcn_mfma_f32_16x16x32_bf16(a10, b0, zero4, 0, 0, 0);
    f32x4 d2 = __builtin_amdgcn_mfma_f32_16x16x32_bf16(a20, b0, zero4, 0, 0, 0);
    f32x4 d3 = __builtin_amdgcn_mfma_f32_16x16x32_bf16(a30, b0, zero4, 0, 0, 0);
    d0 = __builtin_amdgcn_mfma_f32_16x16x32_bf16(a01, b1, d0, 0, 0, 0);
    d1 = __builtin_amdgcn_mfma_f32_16x16x32_bf16(a11, b1, d1, 0, 0, 0);
    d2 = __builtin_amdgcn_mfma_f32_16x16x32_bf16(a21, b1, d2, 0, 0, 0);
    d3 = __builtin_amdgcn_mfma_f32_16x16x32_bf16(a31, b1, d3, 0, 0, 0);
    const bool live = (mv != 0);
#define EPI(dd, eu, ss) { \
    float e0 = __uint_as_float(eu.x << 16); \
    float e1 = __uint_as_float(eu.x & 0xffff0000u); \
    float e2 = __uint_as_float(eu.y << 16); \
    float e3 = __uint_as_float(eu.y & 0xffff0000u); \
    unsigned nx = pk2(dd[1] * e1, dd[0] * e0); \
    unsigned ny = pk2(dd[3] * e3, dd[2] * e2); \
    ss.x = live ? nx : ss.x; \
    ss.y = live ? ny : ss.y; }
    EPI(d0, eu0, st0) EPI(d1, eu1, st1) EPI(d2, eu2, st2) EPI(d3, eu3, st3)
#undef EPI
    NL += (live && tt >= Wc) ? 1 : 0;
  };

  // rounds [0, RT): compute slab r is full -> no per-step guards
  const int RT = (TOT - 4) >> 2;
  for (int r = 0; r < NSLAB; ++r) {
    if (wid == 0) {
      if ((r & 1) == 0) renorm(4 * r);
      const short* cbase = convS[r & 1];
      if (r < RT) {
        #pragma unroll
        for (int u = 0; u < SLAB; ++u)
          scan_step(cbase + (u * 8 + r8) * CROW, 4 * r + u);
      } else {
        #pragma unroll
        for (int u = 0; u < SLAB; ++u)
          if (4 * r + u < TOT)
            scan_step(cbase + (u * 8 + r8) * CROW, 4 * r + u);
      }
    } else if (wid == 1 || wid == 2) {
      // issue slab r+4 into buffer (r+4)&3 == r&3; convert slab r+1.
      switch (r & 3) {
        case 0: LOADS(A, r + 4); CONVW(B, r + 1); break;
        case 1: LOADS(B, r + 4); CONVW(C, r + 1); break;
        case 2: LOADS(C, r + 4); CONVW(D, r + 1); break;
        default: LOADS(D, r + 4); CONVW(A, r + 1); break;
      }
      asm volatile("s_waitcnt lgkmcnt(0)" ::: "memory");  // publish ds_writes
    }
    // wave3: nothing — just the barrier
    __builtin_amdgcn_s_barrier();
    asm volatile("" ::: "memory");
  }
#undef LOADS
#undef CONVW

  // ================= per-chunk outputs =================
  if (wid == 0) {
    float x00, x01, x02, x03, x10, x11, x12, x13;
    float x20, x21, x22, x23, x30, x31, x32, x33;
    UNP(st0, x00, x01, x02, x03) UNP(st1, x10, x11, x12, x13)
    UNP(st2, x20, x21, x22, x23) UNP(st3, x30, x31, x32, x33)
    float sm = (((x00 + x01) + (x02 + x03)) + ((x10 + x11) + (x12 + x13)))
             + (((x20 + x21) + (x22 + x23)) + ((x30 + x31) + (x32 + x33)));
    sm += __shfl_xor(sm, 16); sm += __shfl_xor(sm, 32);
    const int bm = 8 * g + r8;
    float L = __logf(sm) - Slog + LN2 * (float)(7 * NL - K);
    if (q == 0 && m < 8) wsL[c * 256 + bm] = L;
    if (c == NCH - 1 && m < 8) {
      if (q == 0) wsSE[bm] = __logf(sm);
      // permuted export: st0->states 8q+0..3, st1->8q+4..7, st2/st3 +32
      wsA[(8 * q + 0) * 256 + bm] = x00;  wsA[(8 * q + 1) * 256 + bm] = x01;
      wsA[(8 * q + 2) * 256 + bm] = x02;  wsA[(8 * q + 3) * 256 + bm] = x03;
      wsA[(8 * q + 4) * 256 + bm] = x10;  wsA[(8 * q + 5) * 256 + bm] = x11;
      wsA[(8 * q + 6) * 256 + bm] = x12;  wsA[(8 * q + 7) * 256 + bm] = x13;
      wsA[(32 + 8 * q + 0) * 256 + bm] = x20; wsA[(32 + 8 * q + 1) * 256 + bm] = x21;
      wsA[(32 + 8 * q + 2) * 256 + bm] = x22; wsA[(32 + 8 * q + 3) * 256 + bm] = x23;
      wsA[(36 + 8 * q + 0) * 256 + bm] = x30; wsA[(36 + 8 * q + 1) * 256 + bm] = x31;
      wsA[(36 + 8 * q + 2) * 256 + bm] = x32; wsA[(36 + 8 * q + 3) * 256 + bm] = x33;
    }
  }
#undef UNP

  // ================= fused finale (last of 512 blocks) =================
  __threadfence();      // release this block's global stores
  __syncthreads();
  if (tid == 0) lastF = (atomicAdd(cnt, 1) == 511) ? 1 : 0;
  __syncthreads();
  if (lastF) {
    __threadfence();    // acquire all other blocks' stores
    if (tid < 64) eend[tid] = __expf(endt[tid]);
    __syncthreads();
    float vsum = 0.f;
    for (int bb = tid; bb < Bn; bb += 256) {
      float sumL = 0.f, gold = 0.f;
      int msum = 0;
      #pragma unroll
      for (int cc = 0; cc < NCH; ++cc) {
        sumL += wsL[cc * 256 + bb];
        gold += wsGold[cc * 256 + bb];
        msum += wsM[cc * 256 + bb];
      }
      msum += mask[(size_t)bb * Sn];  // t = 0
      float se = 0.f;
      for (int jj = 0; jj < Tn; ++jj) se += wsA[jj * 256 + bb] * eend[jj];
      float logZ = sumL + __logf(se) - wsSE[bb];
      int tg0 = tags[(size_t)bb * Sn];
      int lastTag = tags[(size_t)bb * Sn + (msum - 1)];
      gold += startt[tg0] + em[(size_t)bb * Sn * Tn + tg0] + endt[lastTag];
      vsum += logZ - gold;
    }
    #pragma unroll
    for (int o = 32; o > 0; o >>= 1) vsum += __shfl_xor(vsum, o, 64);
    if (lane == 0) rsum[wid] = vsum;
    __syncthreads();
    if (tid == 0) out[0] = (rsum[0] + rsum[1] + rsum[2] + rsum[3]) * (1.0f / Bn);
  }
}

extern "C" void kernel_launch(void* const* d_in, const int* in_sizes, int n_in,
                              void* d_out, int out_size, void* d_ws, size_t ws_size,
                              hipStream_t stream) {
  const float* em     = (const float*)d_in[0];
  const int*   tags   = (const int*)d_in[1];
  const int*   mask   = (const int*)d_in[2];
  const float* trans  = (const float*)d_in[3];
  const float* startt = (const float*)d_in[4];
  const float* endt   = (const float*)d_in[5];
  float* out = (float*)d_out;

  float* wsL    = (float*)d_ws;               // [16*256]
  float* wsGold = wsL + NCH * 256;            // [16*256]
  int*   wsM    = (int*)(wsGold + NCH * 256); // [16*256]
  float* wsSE   = (float*)(wsM + NCH * 256);  // [256]
  float* wsA    = wsSE + 256;                 // [64*256]
  int*   cnt    = (int*)(wsA + 64 * 256);     // [1] last-block counter

  hipMemsetAsync(cnt, 0, sizeof(int), stream);  // ws is poisoned 0xAA pre-launch
  crf_scan<<<512, 256, 0, stream>>>(em, tags, mask, trans, startt, endt,
                                    wsL, wsGold, wsM, wsSE, wsA, cnt, out);
}

// Round 10
// 161.188 us; speedup vs baseline: 1.1360x; 1.1360x over previous
//
#include <hip/hip_runtime.h>

#define Bn 256
#define Sn 1024
#define Tn 64
#define NCH 16
#define BURN 64
#define SLAB 4
#define RAWSTR 260          // raw f32 per-mm stride (256 + 4 pad: 2-way banks)
#define CROW 72             // conv bf16 row stride in shorts
#define MROW 129
#define LN2 0.69314718055994531f
#define L7LN2 4.8520302639196169f   // 7*ln2 (lambda = 2^-7 folded into exp)

typedef __attribute__((ext_vector_type(8))) short short8;
typedef __attribute__((ext_vector_type(4))) float f32x4;

__device__ __forceinline__ unsigned short f2bf_rne(float f) {
  unsigned u = __float_as_uint(f);
  u = (u + 0x7fffu + ((u >> 16) & 1u)) >> 16;
  return (unsigned short)u;
}
__device__ __forceinline__ unsigned pk2(float hi, float lo) {
  return __builtin_amdgcn_perm(__float_as_uint(hi), __float_as_uint(lo), 0x07060302);
}
__device__ __forceinline__ unsigned pke(float a, float b) {  // exp+pack 2 bf16
  return (unsigned)f2bf_rne(__expf(a - L7LN2)) |
         ((unsigned)f2bf_rne(__expf(b - L7LN2)) << 16);
}
// concat two uint2 (4 bf16 each) into a short8 MFMA operand — register-only.
__device__ __forceinline__ short8 cat4(uint2 a, uint2 b) {
  union { unsigned u[4]; short8 s; } x;
  x.u[0] = a.x; x.u[1] = a.y; x.u[2] = b.x; x.u[3] = b.y;
  return x.s;
}
// async global->LDS: no dest VGPRs -> pipelined by construction.
__device__ __forceinline__ void gl_lds16(const void* src, void* dst) {
  __builtin_amdgcn_global_load_lds(
      (const __attribute__((address_space(1))) void*)src,
      (__attribute__((address_space(3))) void*)dst, 16, 0, 0);
}
__device__ __forceinline__ void gl_lds4(const void* src, void* dst) {
  __builtin_amdgcn_global_load_lds(
      (const __attribute__((address_space(1))) void*)src,
      (__attribute__((address_space(3))) void*)dst, 4, 0, 0);
}

// R10: ROLE-PURE PIPELINE (no structural vmcnt drain). R1-R9 audit: every
// variant had a wave with BOTH outstanding vmem and an LDS read the compiler
// had to order against it -> conservative s_waitcnt vmcnt(0) every round ->
// round time = full slab-delivery latency (~6k cy), BW artifact ~2.5 B/cy.
// Fix: strict purity so nobody drains:
//   wave0: PURE scan   (ds_read convS/maskL + MFMA; zero vmem in loop)
//   wave1: PURE conv u={0,1} (ds_read rawS -> pke -> ds_write convS; no vmem)
//   wave2: PURE conv u={2,3}
//   wave3: PURE producer (16x gl_lds16 slab r+3; hand-counted vmcnt(16)
//          leaves it in flight; NEVER reads LDS or registers from loads)
// rawS = 3-deep ring (slabs r+1 read / r+2,r+3 in flight are distinct mod 3).
// All prologue vmem drained once pre-rounds. Raw s_barrier (no implicit drain).
// Register-resident alpha via permuted A rows (rho) — D-layout == B-layout.
// Fused finale: last block (atomic count) reduces everything to out[0].
__global__ __launch_bounds__(256, 1) void crf_scan(
    const float* __restrict__ em, const int* __restrict__ tags,
    const int* __restrict__ mask, const float* __restrict__ trans,
    const float* __restrict__ startt, const float* __restrict__ endt,
    float* __restrict__ wsL, float* __restrict__ wsGold,
    int* __restrict__ wsM, float* __restrict__ wsSE, float* __restrict__ wsA,
    int* __restrict__ cnt, float* __restrict__ out) {
  const int g = blockIdx.x & 15;
  const int c = blockIdx.x >> 4;
  const int Wc = (c == 0) ? 0 : BURN;
  const int Lc = (c == NCH - 1) ? 63 : 64;
  const int TOT = Wc + Lc;
  const int NSLAB = (TOT + SLAB - 1) / SLAB;
  const int t0 = 64 * c + 1;
  const int tstart = t0 - Wc;
  const int tid = threadIdx.x;
  const int wid = tid >> 6;
  const int lane = tid & 63;
  const int m = lane & 15;
  const int q = lane >> 4;
  const int mrow = 8 * (m >> 2) + (m & 3);  // permuted A-row base for this lane

  __shared__ __align__(16) float rawS[3][16 * RAWSTR];      // 49.9 KB raw em ring
  __shared__ __align__(16) short convS[2][SLAB * 16 * CROW];// 18.4 KB exp'd bf16
  __shared__ int maskL[16 * MROW];                          // 8.3 KB
  __shared__ int lastF;
  __shared__ float eend[64];
  __shared__ float rsum[4];

  short8 a00, a01, a10, a11, a20, a21, a30, a31;
  uint2 st0, st1, st2, st3;
  float Slog = 0.f;
  int K = 0, NL = 0;
  const f32x4 zero4 = {0.f, 0.f, 0.f, 0.f};

  // -------- producer (wave3) / converter (waves 1,2) helpers --------
  auto issue_slab = [&](int s) {   // 16x gl_lds16 (full) or 16*rem gl_lds4
    if (s >= NSLAB) return;
    float* dstb = rawS[s % 3];
    const int rem = TOT - 4 * s;
    if (rem >= SLAB) {
      for (int mm = 0; mm < 16; ++mm)
        gl_lds16(em + ((size_t)(16 * g + mm) * Sn + tstart + 4 * s) * 64 + lane * 4,
                 dstb + mm * RAWSTR);
    } else {  // only c==0 / c==15 last slab; per-step loads keep t <= 1023
      for (int mm = 0; mm < 16; ++mm)
        for (int u = 0; u < rem; ++u)
          gl_lds4(em + ((size_t)(16 * g + mm) * Sn + tstart + 4 * s + u) * 64 + lane,
                  dstb + mm * RAWSTR + u * 64);
    }
  };
  // Writes exp'd emissions in the PERMUTED state order (see R1 derivation).
  auto conv_u = [&](const float* rp, short* cb, int mm, int base, int u) {
    float4 v0 = *(const float4*)(rp + u * 64 + 0);
    float4 v1 = *(const float4*)(rp + u * 64 + 4);
    float4 v2 = *(const float4*)(rp + u * 64 + 8);
    float4 v3 = *(const float4*)(rp + u * 64 + 12);
    uint4 o0, o1;
    o0.x = pke(v0.x, v0.y); o0.y = pke(v0.z, v0.w);   // states +0..3
    o1.x = pke(v1.x, v1.y); o1.y = pke(v1.z, v1.w);   // states +4..7
    o0.z = pke(v2.x, v2.y); o0.w = pke(v2.z, v2.w);   // states +8..11
    o1.z = pke(v3.x, v3.y); o1.w = pke(v3.z, v3.w);   // states +12..15
    short* cw = cb + (u * 16 + mm) * CROW + base;
    *(uint4*)(cw) = o0;
    *(uint4*)(cw + 16) = o1;
  };
  auto convert2 = [&](int s, int ua) {  // two u values, compile-time unrolled
    const int mm = lane & 15, seg = lane >> 4;
    const float* rp = rawS[s % 3] + mm * RAWSTR + seg * 16;
    short* cb = convS[s & 1];
    const int base = (seg >> 1) * 32 + (seg & 1) * 8;
    conv_u(rp, cb, mm, base, ua);
    conv_u(rp, cb, mm, base, ua + 1);
  };
  auto convert_tail2 = [&](int s, int ua) {
    if (s >= NSLAB) return;
    const int mm = lane & 15, seg = lane >> 4;
    const float* rp = rawS[s % 3] + mm * RAWSTR + seg * 16;
    short* cb = convS[s & 1];
    const int base = (seg >> 1) * 32 + (seg & 1) * 8;
    const int vu = min(SLAB, TOT - 4 * s);
    const int ub = min(vu, ua + 2);
    for (int u = ua; u < ub; ++u) conv_u(rp, cb, mm, base, u);
  };

  // ================= prologue (all vmem here, drained before rounds) ====
  if (wid == 0) {
    // A_phys[j][k] = exp(trans[k][rho(j)]); rho(16tm+m) = 32(tm>>1)+4(tm&1)+mrow
#define LOADA(tm, kc, dst) { \
    _Pragma("unroll") for (int jj = 0; jj < 8; ++jj) { \
      int kk = kc * 32 + q * 8 + jj; \
      dst[jj] = (short)f2bf_rne(__expf(trans[kk * Tn + (32 * ((tm) >> 1) + 4 * ((tm) & 1) + mrow)])); \
    } }
    LOADA(0, 0, a00) LOADA(0, 1, a01) LOADA(1, 0, a10) LOADA(1, 1, a11)
    LOADA(2, 0, a20) LOADA(2, 1, a21) LOADA(3, 0, a30) LOADA(3, 1, a31)
#undef LOADA
    if (c == 0) {  // exact alpha_0 = exp(startt + em[:,0,:]), permuted slots
#define INIT0(off, ss) { \
      float4 sv = *(const float4*)(startt + (off)); \
      float4 ev = *(const float4*)(em + (size_t)(16 * g + m) * Sn * Tn + (off)); \
      ss.x = (unsigned)f2bf_rne(__expf(sv.x + ev.x)) | \
             ((unsigned)f2bf_rne(__expf(sv.y + ev.y)) << 16); \
      ss.y = (unsigned)f2bf_rne(__expf(sv.z + ev.z)) | \
             ((unsigned)f2bf_rne(__expf(sv.w + ev.w)) << 16); }
      INIT0(8 * q, st0) INIT0(8 * q + 4, st1)
      INIT0(32 + 8 * q, st2) INIT0(36 + 8 * q, st3)
#undef INIT0
    } else {
      st0.x = 0x3F803F80u; st0.y = 0x3F803F80u; st1 = st0; st2 = st0; st3 = st0;
    }
    // mask repair for the one special row (plain global load -> ds_write);
    // wave3 skips this slot, so no race. Published at B1 via lgkmcnt(0).
    if (c == NCH - 1 && g == 15) {
      int t = tstart + 64 + lane;
      if (t < Sn) maskL[15 * MROW + 64 + lane] = mask[(size_t)255 * Sn + t];
    }
    asm volatile("s_waitcnt vmcnt(0) lgkmcnt(0)" ::: "memory");
  } else if (wid == 1) {
    // ---- gold partials (prologue vmem only) ----
    const int bm = 16 * g + m;
    const int* tg = tags + (size_t)bm * Sn;
    const int* mkb = mask + (size_t)bm * Sn;
    const float* emb = em + (size_t)bm * Sn * Tn;
    float acc = 0.f;
    int cntg = 0;
    #pragma unroll 4
    for (int i = 0; i < 16; ++i) {
      int t = t0 + q + 4 * i;
      bool ok = t < t0 + Lc;
      int ts = ok ? t : t0;
      int mv = mkb[ts];
      int tp = tg[ts - 1], tc = tg[ts];
      float w = trans[tp * Tn + tc] + emb[(size_t)ts * Tn + tc];
      acc += (ok && mv) ? w : 0.f;
      cntg += ok ? mv : 0;
    }
    acc += __shfl_xor(acc, 16); acc += __shfl_xor(acc, 32);
    cntg += __shfl_xor(cntg, 16); cntg += __shfl_xor(cntg, 32);
    if (q == 0) { wsGold[c * 256 + bm] = acc; wsM[c * 256 + bm] = cntg; }
    asm volatile("s_waitcnt vmcnt(0)" ::: "memory");
  } else if (wid == 2) {
    // nothing (pure converter; stays vmem-free for the whole kernel loop)
  } else {
    // producer: mask gl_lds first, then slabs 0-2; counted wait: mask+slab0
    // done, slabs 1-2 (32 loads) stay in flight across B1.
    for (int mm = 0; mm < 16; ++mm) {
      gl_lds4(mask + (size_t)(16 * g + mm) * Sn + tstart + lane,
              (void*)(maskL + mm * MROW));
      bool special = (c == NCH - 1) && (g == 15) && (mm == 15);  // OOB t=1024
      if (!special)
        gl_lds4(mask + (size_t)(16 * g + mm) * Sn + tstart + 64 + lane,
                (void*)(maskL + mm * MROW + 64));
    }
    issue_slab(0); issue_slab(1); issue_slab(2);
    asm volatile("s_waitcnt vmcnt(32)" ::: "memory");
  }
  __builtin_amdgcn_s_barrier();   // B1: maskL + rawS[0] ready; slabs 1,2 flying
  asm volatile("" ::: "memory");

  // ================= phase P =================
  if (wid == 1) { convert2(0, 0); asm volatile("s_waitcnt lgkmcnt(0)" ::: "memory"); }
  else if (wid == 2) { convert2(0, 2); asm volatile("s_waitcnt lgkmcnt(0)" ::: "memory"); }
  else if (wid == 3) { asm volatile("s_waitcnt vmcnt(16)" ::: "memory"); }  // slab1 done
  __builtin_amdgcn_s_barrier();   // B2: convS[0] + rawS[1] ready; slab2 flying
  asm volatile("" ::: "memory");

  // ================= rounds =================
#define UNP(ss, x0, x1, x2, x3) \
  x0 = __uint_as_float(ss.x << 16); x1 = __uint_as_float(ss.x & 0xffff0000u); \
  x2 = __uint_as_float(ss.y << 16); x3 = __uint_as_float(ss.y & 0xffff0000u);

  auto renorm = [&](int ttz) {  // every 8 steps, exact pow2 scaling
    float x00, x01, x02, x03, x10, x11, x12, x13;
    float x20, x21, x22, x23, x30, x31, x32, x33;
    UNP(st0, x00, x01, x02, x03) UNP(st1, x10, x11, x12, x13)
    UNP(st2, x20, x21, x22, x23) UNP(st3, x30, x31, x32, x33)
    float sm = (((x00 + x01) + (x02 + x03)) + ((x10 + x11) + (x12 + x13)))
             + (((x20 + x21) + (x22 + x23)) + ((x30 + x31) + (x32 + x33)));
    sm += __shfl_xor(sm, 16); sm += __shfl_xor(sm, 32);
    if (c != 0 && ttz == BURN) { Slog = __logf(sm); K = 0; NL = 0; }
    int k = 127 - (int)((__float_as_uint(sm) >> 23) & 255u);
    float fk = __uint_as_float((unsigned)(127 + k) << 23);
    x00 *= fk; x01 *= fk; x02 *= fk; x03 *= fk;
    x10 *= fk; x11 *= fk; x12 *= fk; x13 *= fk;
    x20 *= fk; x21 *= fk; x22 *= fk; x23 *= fk;
    x30 *= fk; x31 *= fk; x32 *= fk; x33 *= fk;
    st0.x = pk2(x01, x00); st0.y = pk2(x03, x02);
    st1.x = pk2(x11, x10); st1.y = pk2(x13, x12);
    st2.x = pk2(x21, x20); st2.y = pk2(x23, x22);
    st3.x = pk2(x31, x30); st3.y = pk2(x33, x32);
    K += k;
  };

  auto scan_step = [&](const short* ep, int tt) {
    uint2 eu0 = *(const uint2*)(ep + 0 + 4 * q);
    uint2 eu1 = *(const uint2*)(ep + 16 + 4 * q);
    uint2 eu2 = *(const uint2*)(ep + 32 + 4 * q);
    uint2 eu3 = *(const uint2*)(ep + 48 + 4 * q);
    int mv = maskL[m * MROW + tt];
    // D-layout == B-layout under the row permutation: pure reg concat.
    short8 b0 = cat4(st0, st1);
    short8 b1 = cat4(st2, st3);
    f32x4 d0 = __builtin_amdgcn_mfma_f32_16x16x32_bf16(a00, b0, zero4, 0, 0, 0);
    f32x4 d1 = __builtin_amdgcn_mfma_f32_16x16x32_bf16(a10, b0, zero4, 0, 0, 0);
    f32x4 d2 = __builtin_amdgcn_mfma_f32_16x16x32_bf16(a20, b0, zero4, 0, 0, 0);
    f32x4 d3 = __builtin_amdgcn_mfma_f32_16x16x32_bf16(a30, b0, zero4, 0, 0, 0);
    d0 = __builtin_amdgcn_mfma_f32_16x16x32_bf16(a01, b1, d0, 0, 0, 0);
    d1 = __builtin_amdgcn_mfma_f32_16x16x32_bf16(a11, b1, d1, 0, 0, 0);
    d2 = __builtin_amdgcn_mfma_f32_16x16x32_bf16(a21, b1, d2, 0, 0, 0);
    d3 = __builtin_amdgcn_mfma_f32_16x16x32_bf16(a31, b1, d3, 0, 0, 0);
    const bool live = (mv != 0);
#define EPI(dd, eu, ss) { \
    float e0 = __uint_as_float(eu.x << 16); \
    float e1 = __uint_as_float(eu.x & 0xffff0000u); \
    float e2 = __uint_as_float(eu.y << 16); \
    float e3 = __uint_as_float(eu.y & 0xffff0000u); \
    unsigned nx = pk2(dd[1] * e1, dd[0] * e0); \
    unsigned ny = pk2(dd[3] * e3, dd[2] * e2); \
    ss.x = live ? nx : ss.x; \
    ss.y = live ? ny : ss.y; }
    EPI(d0, eu0, st0) EPI(d1, eu1, st1) EPI(d2, eu2, st2) EPI(d3, eu3, st3)
#undef EPI
    NL += (live && tt >= Wc) ? 1 : 0;
  };

  // rounds [0, RT): compute slab r is full -> no per-step guards
  const int RT = (TOT - 4) >> 2;
  for (int r = 0; r < NSLAB; ++r) {
    if (wid == 0) {
      if ((r & 1) == 0) renorm(4 * r);
      const short* cbase = convS[r & 1];
      if (r < RT) {
        #pragma unroll
        for (int u = 0; u < SLAB; ++u)
          scan_step(cbase + (u * 16 + m) * CROW, 4 * r + u);
      } else {
        #pragma unroll
        for (int u = 0; u < SLAB; ++u)
          if (4 * r + u < TOT)
            scan_step(cbase + (u * 16 + m) * CROW, 4 * r + u);
      }
    } else if (wid == 1) {
      if (r + 1 < RT) convert2(r + 1, 0);
      else            convert_tail2(r + 1, 0);
      asm volatile("s_waitcnt lgkmcnt(0)" ::: "memory");
    } else if (wid == 2) {
      if (r + 1 < RT) convert2(r + 1, 2);
      else            convert_tail2(r + 1, 2);
      asm volatile("s_waitcnt lgkmcnt(0)" ::: "memory");
    } else {
      const int nxt = r + 3;
      issue_slab(nxt);                 // into rawS[nxt%3] == rawS[r%3]
      if (nxt < NSLAB) {
        if (TOT - 4 * nxt >= SLAB) asm volatile("s_waitcnt vmcnt(16)" ::: "memory");
        else                       asm volatile("s_waitcnt vmcnt(48)" ::: "memory");
      } else {
        asm volatile("s_waitcnt vmcnt(0)" ::: "memory");  // tail drain (cheap)
      }
    }
    __builtin_amdgcn_s_barrier();
    asm volatile("" ::: "memory");
  }

  // ================= per-chunk outputs =================
  if (wid == 0) {
    float x00, x01, x02, x03, x10, x11, x12, x13;
    float x20, x21, x22, x23, x30, x31, x32, x33;
    UNP(st0, x00, x01, x02, x03) UNP(st1, x10, x11, x12, x13)
    UNP(st2, x20, x21, x22, x23) UNP(st3, x30, x31, x32, x33)
    float sm = (((x00 + x01) + (x02 + x03)) + ((x10 + x11) + (x12 + x13)))
             + (((x20 + x21) + (x22 + x23)) + ((x30 + x31) + (x32 + x33)));
    sm += __shfl_xor(sm, 16); sm += __shfl_xor(sm, 32);
    const int bm = 16 * g + m;
    float L = __logf(sm) - Slog + LN2 * (float)(7 * NL - K);
    if (q == 0) wsL[c * 256 + bm] = L;
    if (c == NCH - 1) {
      if (q == 0) wsSE[bm] = __logf(sm);
      // permuted export: st0->states 8q+0..3, st1->8q+4..7, st2/st3 +32
      wsA[(8 * q + 0) * 256 + bm] = x00;  wsA[(8 * q + 1) * 256 + bm] = x01;
      wsA[(8 * q + 2) * 256 + bm] = x02;  wsA[(8 * q + 3) * 256 + bm] = x03;
      wsA[(8 * q + 4) * 256 + bm] = x10;  wsA[(8 * q + 5) * 256 + bm] = x11;
      wsA[(8 * q + 6) * 256 + bm] = x12;  wsA[(8 * q + 7) * 256 + bm] = x13;
      wsA[(32 + 8 * q + 0) * 256 + bm] = x20; wsA[(32 + 8 * q + 1) * 256 + bm] = x21;
      wsA[(32 + 8 * q + 2) * 256 + bm] = x22; wsA[(32 + 8 * q + 3) * 256 + bm] = x23;
      wsA[(36 + 8 * q + 0) * 256 + bm] = x30; wsA[(36 + 8 * q + 1) * 256 + bm] = x31;
      wsA[(36 + 8 * q + 2) * 256 + bm] = x32; wsA[(36 + 8 * q + 3) * 256 + bm] = x33;
    }
  }
#undef UNP

  // ================= fused finale (last block) =================
  __threadfence();      // release this block's global stores
  __syncthreads();
  if (tid == 0) lastF = (atomicAdd(cnt, 1) == 255) ? 1 : 0;
  __syncthreads();
  if (lastF) {
    __threadfence();    // acquire all other blocks' stores
    if (tid < 64) eend[tid] = __expf(endt[tid]);
    __syncthreads();
    float vsum = 0.f;
    for (int bb = tid; bb < Bn; bb += 256) {
      float sumL = 0.f, gold = 0.f;
      int msum = 0;
      #pragma unroll
      for (int cc = 0; cc < NCH; ++cc) {
        sumL += wsL[cc * 256 + bb];
        gold += wsGold[cc * 256 + bb];
        msum += wsM[cc * 256 + bb];
      }
      msum += mask[(size_t)bb * Sn];  // t = 0
      float se = 0.f;
      for (int jj = 0; jj < Tn; ++jj) se += wsA[jj * 256 + bb] * eend[jj];
      float logZ = sumL + __logf(se) - wsSE[bb];
      int tg0 = tags[(size_t)bb * Sn];
      int lastTag = tags[(size_t)bb * Sn + (msum - 1)];
      gold += startt[tg0] + em[(size_t)bb * Sn * Tn + tg0] + endt[lastTag];
      vsum += logZ - gold;
    }
    #pragma unroll
    for (int o = 32; o > 0; o >>= 1) vsum += __shfl_xor(vsum, o, 64);
    if (lane == 0) rsum[wid] = vsum;
    __syncthreads();
    if (tid == 0) out[0] = (rsum[0] + rsum[1] + rsum[2] + rsum[3]) * (1.0f / Bn);
  }
}

extern "C" void kernel_launch(void* const* d_in, const int* in_sizes, int n_in,
                              void* d_out, int out_size, void* d_ws, size_t ws_size,
                              hipStream_t stream) {
  const float* em     = (const float*)d_in[0];
  const int*   tags   = (const int*)d_in[1];
  const int*   mask   = (const int*)d_in[2];
  const float* trans  = (const float*)d_in[3];
  const float* startt = (const float*)d_in[4];
  const float* endt   = (const float*)d_in[5];
  float* out = (float*)d_out;

  float* wsL    = (float*)d_ws;               // [16*256]
  float* wsGold = wsL + NCH * 256;            // [16*256]
  int*   wsM    = (int*)(wsGold + NCH * 256); // [16*256]
  float* wsSE   = (float*)(wsM + NCH * 256);  // [256]
  float* wsA    = wsSE + 256;                 // [64*256]
  int*   cnt    = (int*)(wsA + 64 * 256);     // [1] last-block counter

  hipMemsetAsync(cnt, 0, sizeof(int), stream);  // ws is poisoned 0xAA pre-launch
  crf_scan<<<256, 256, 0, stream>>>(em, tags, mask, trans, startt, endt,
                                    wsL, wsGold, wsM, wsSE, wsA, cnt, out);
}